// Round 13
// baseline (158.235 us; speedup 1.0000x reference)
//
#include <hip/hip_runtime.h>

// QuantumTextClassifier: embed+PE -> 4x {q=cumprod(cos(x)); x=LN(x+q); x=LN(x+q)}
// -> mean over T -> @W + b.
// r13 = r9 (best: 28.2us) + fused finalization (single dispatch):
//  - Mapping: 4 rows/wave (16 lanes/row, 8 elems/lane = 4x float2), 2 chains
//    (A,B) per wave; ALL LN params hoisted to registers; (256,4) launch bounds
//    (r12 proved (256,8) triggers catastrophic scratch spill: 350MB/dispatch).
//  - Pooling: block LDS reduce -> atomicAdd into pooled[B,E] (device-coherent);
//    __threadfence + counter atomicAdd; LAST block per batch re-reads pooled
//    via agent-scope atomic loads and does the tiny matmul inline.
//    Saves the second kernel dispatch + its gap. Fixed reduce order -> determ.

#define NBLK 4
#define E_DIM 128
#define T_LEN 2048
#define B_SZ 32
#define C_CLS 4
#define LN_EPS 1e-5f
#define WG_PER_B 64                         // workgroups per batch element
#define WAVES_PER_WG 4
#define NUM_WG (B_SZ * WG_PER_B)            // 2048

#define F_ONE 0x3F800000                    // bit pattern of 1.0f

typedef float v2f __attribute__((ext_vector_type(2)));
typedef float v4f __attribute__((ext_vector_type(4)));

// DPP move with old-value semantics (invalid/masked lanes -> OLD bits).
template <int CTRL, int RMASK, int OLDBITS>
__device__ __forceinline__ float dppf(float v) {
    return __int_as_float(__builtin_amdgcn_update_dpp(
        OLDBITS, __float_as_int(v), CTRL, RMASK, 0xF, false));
}

// Fused-add DPP step (bound_ctrl=1: invalid lanes contribute 0).
template <int CTRL>
__device__ __forceinline__ float dpp_add(float s) {
    return s + __int_as_float(__builtin_amdgcn_update_dpp(
        0, __float_as_int(s), CTRL, 0xF, 0xF, true));
}

// Sum over each 16-lane row; result broadcast to every lane of the row.
__device__ __forceinline__ float row16_sum(float s) {
    s = dpp_add<0xB1>(s);    // quad_perm [1,0,3,2]  ~ xor1
    s = dpp_add<0x4E>(s);    // quad_perm [2,3,0,1]  ~ xor2
    s = dpp_add<0x141>(s);   // row_half_mirror      ~ xor4
    s = dpp_add<0x140>(s);   // row_mirror           ~ xor8
    return s;
}

__device__ __forceinline__ v4f ld4(const float* p) {
    return *reinterpret_cast<const v4f*>(p);
}

// cumprod(cos(X)) along the 128-elem row (16 lanes x 4 v2f): Q = prefix prods.
__device__ __forceinline__ void cumq_v(const v2f* __restrict__ X,
                                       v2f* __restrict__ Q) {
    const float c0 = __cosf(X[0].x), c1 = __cosf(X[0].y);
    const float c2 = __cosf(X[1].x), c3 = __cosf(X[1].y);
    const float c4 = __cosf(X[2].x), c5 = __cosf(X[2].y);
    const float c6 = __cosf(X[3].x), c7 = __cosf(X[3].y);
    const float p23 = c2 * c3, p45 = c4 * c5, p67 = c6 * c7;
    const float P2 = c0 * c1;
    const float P4 = P2 * p23;
    const float P6 = P4 * p45;
    const float P8 = P6 * p67;         // lane's 8-elem product
    const float P3 = P2 * c2;
    const float P5 = P4 * c4;
    const float P7 = P6 * c6;
    float sc = P8;                     // inclusive scan over 16 lanes
    sc *= dppf<0x111, 0xF, F_ONE>(sc); // row_shr:1
    sc *= dppf<0x112, 0xF, F_ONE>(sc); // row_shr:2
    sc *= dppf<0x114, 0xF, F_ONE>(sc); // row_shr:4
    sc *= dppf<0x118, 0xF, F_ONE>(sc); // row_shr:8
    // exclusive: shift by 1; row-head lanes auto-get old=1.0
    const float ex = dppf<0x111, 0xF, F_ONE>(sc);
    const v2f exv = {ex, ex};
    Q[0] = exv * (v2f){c0, P2};
    Q[1] = exv * (v2f){P3, P4};
    Q[2] = exv * (v2f){P5, P6};
    Q[3] = exv * (v2f){P7, P8};
}

// LayerNorm over a 128-elem row held as 16 lanes x 4 float2 (params in regs).
__device__ __forceinline__ void ln8v(const v2f* __restrict__ Y,
                                     const v2f* __restrict__ g,
                                     const v2f* __restrict__ be,
                                     v2f* __restrict__ o) {
    v2f sv = (Y[0] + Y[1]) + (Y[2] + Y[3]);
    v2f qv = Y[0] * Y[0];
    qv = __builtin_elementwise_fma(Y[1], Y[1], qv);
    qv = __builtin_elementwise_fma(Y[2], Y[2], qv);
    qv = __builtin_elementwise_fma(Y[3], Y[3], qv);
    const float S  = row16_sum(sv.x + sv.y);
    const float S2 = row16_sum(qv.x + qv.y);
    const float mu  = S * (1.0f / 128.0f);
    const float var = fmaf(S2, 1.0f / 128.0f, -mu * mu);
    const float r   = rsqrtf(var + LN_EPS);
    const v2f muv = {mu, mu};
    const v2f rv  = {r, r};
    #pragma unroll
    for (int j = 0; j < 4; ++j)
        o[j] = __builtin_elementwise_fma((Y[j] - muv) * rv, g[j], be[j]);
}

// Fused-add DPP over full wave (total lands in lane 63).
__device__ __forceinline__ float wave_sum_tail(float s) {
    s = dpp_add<0xB1>(s);
    s = dpp_add<0x4E>(s);
    s = dpp_add<0x141>(s);
    s = dpp_add<0x140>(s);
    s = s + __int_as_float(__builtin_amdgcn_update_dpp(
        0, __float_as_int(s), 0x142, 0xA, 0xF, true));   // row_bcast15 -> rows 1,3
    s = s + __int_as_float(__builtin_amdgcn_update_dpp(
        0, __float_as_int(s), 0x143, 0xC, 0xF, true));   // row_bcast31 -> rows 2,3
    return s;
}

template <bool FUSED>
__global__ __launch_bounds__(256, 4) void qtc_main(
    const int*   __restrict__ tokens,   // [B, T]
    const float* __restrict__ emb,      // [V, E]
    const float* __restrict__ g1,       // [NBLK, E]
    const float* __restrict__ b1,
    const float* __restrict__ g2,
    const float* __restrict__ b2,
    const float* __restrict__ W,        // [E, C]
    const float* __restrict__ bias,     // [C]
    float*       __restrict__ pooled,   // [B, E] accumulator (pre-zeroed)
    int*         __restrict__ counters, // [B] (pre-zeroed)
    float*       __restrict__ out)      // [B, C]
{
    __shared__ float part[WAVES_PER_WG][4][E_DIM];   // 8 KB
    __shared__ float pool2[E_DIM];
    __shared__ int   last_flag;

    const int tid  = threadIdx.x;
    const int lane = tid & 63;
    const int wave = tid >> 6;
    const int b    = blockIdx.x / WG_PER_B;
    const int wgb  = blockIdx.x % WG_PER_B;
    const int row  = lane >> 4;          // which of the wave's 4 rows
    const int sub  = lane & 15;          // lane within row
    const int e0   = sub * 8;            // first of 8 contiguous elems
    const int wid  = wgb * WAVES_PER_WG + wave;     // [0, 256) within batch

    // ---- hoist ALL LN params into registers (64 VGPR) ----
    v2f G1[NBLK][4], B1[NBLK][4], G2[NBLK][4], B2[NBLK][4];
    #pragma unroll
    for (int i = 0; i < NBLK; ++i) {
        const v4f a1 = ld4(g1 + i * E_DIM + e0), a2 = ld4(g1 + i * E_DIM + e0 + 4);
        const v4f c1v = ld4(b1 + i * E_DIM + e0), c2v = ld4(b1 + i * E_DIM + e0 + 4);
        const v4f d1 = ld4(g2 + i * E_DIM + e0), d2 = ld4(g2 + i * E_DIM + e0 + 4);
        const v4f e1 = ld4(b2 + i * E_DIM + e0), e2 = ld4(b2 + i * E_DIM + e0 + 4);
        G1[i][0] = a1.xy;  G1[i][1] = a1.zw;  G1[i][2] = a2.xy;  G1[i][3] = a2.zw;
        B1[i][0] = c1v.xy; B1[i][1] = c1v.zw; B1[i][2] = c2v.xy; B1[i][3] = c2v.zw;
        G2[i][0] = d1.xy;  G2[i][1] = d1.zw;  G2[i][2] = d2.xy;  G2[i][3] = d2.zw;
        B2[i][0] = e1.xy;  B2[i][1] = e1.zw;  B2[i][2] = e2.xy;  B2[i][3] = e2.zw;
    }

    // ---- two token positions, PE computed directly ----
    const int   ta   = wid * 4 + row;          // token index A (< 1024)
    const int   tix  = b * T_LEN + ta;
    const int   tokA = tokens[tix];
    const int   tokB = tokens[tix + 1024];
    const float tfA  = (float)ta;
    const float tfB  = (float)(ta + 1024);

    v2f Xa[4], Xb[4];
    {
        const v4f a0  = ld4(&emb[tokA * E_DIM + e0]);
        const v4f a1  = ld4(&emb[tokA * E_DIM + e0 + 4]);
        const v4f b0  = ld4(&emb[tokB * E_DIM + e0]);
        const v4f b1v = ld4(&emb[tokB * E_DIM + e0 + 4]);
        const v2f ea[4] = {a0.xy, a0.zw, a1.xy, a1.zw};
        const v2f eb[4] = {b0.xy, b0.zw, b1v.xy, b1v.zw};
        #pragma unroll
        for (int j = 0; j < 4; ++j) {
            const float f = __expf(-(float)(e0 + 2 * j) * (9.210340371976184f / 128.0f));
            Xa[j] = ea[j] + (v2f){__sinf(tfA * f), __cosf(tfA * f)};
            Xb[j] = eb[j] + (v2f){__sinf(tfB * f), __cosf(tfB * f)};
        }
    }

    // ---- 4 transformer-sim blocks, two independent chains (A,B) ----
    #pragma unroll
    for (int i = 0; i < NBLK; ++i) {
        v2f Qa[4], Qb[4], Y[4];
        cumq_v(Xa, Qa);
        cumq_v(Xb, Qb);
        #pragma unroll
        for (int k = 0; k < 4; ++k) Y[k] = Xa[k] + Qa[k];
        ln8v(Y, G1[i], B1[i], Xa);
        #pragma unroll
        for (int k = 0; k < 4; ++k) Y[k] = Xb[k] + Qb[k];
        ln8v(Y, G1[i], B1[i], Xb);
        #pragma unroll
        for (int k = 0; k < 4; ++k) Y[k] = Xa[k] + Qa[k];
        ln8v(Y, G2[i], B2[i], Xa);
        #pragma unroll
        for (int k = 0; k < 4; ++k) Y[k] = Xb[k] + Qb[k];
        ln8v(Y, G2[i], B2[i], Xb);
    }

    // ---- block-level pooling -> device atomics into pooled[B,E] ----
    const v4f lo = {Xa[0].x + Xb[0].x, Xa[0].y + Xb[0].y,
                    Xa[1].x + Xb[1].x, Xa[1].y + Xb[1].y};
    const v4f hi = {Xa[2].x + Xb[2].x, Xa[2].y + Xb[2].y,
                    Xa[3].x + Xb[3].x, Xa[3].y + Xb[3].y};
    *reinterpret_cast<v4f*>(&part[wave][row][e0])     = lo;
    *reinterpret_cast<v4f*>(&part[wave][row][e0 + 4]) = hi;
    __syncthreads();
    if (tid < E_DIM) {
        float s = 0.0f;
        #pragma unroll
        for (int w = 0; w < WAVES_PER_WG; ++w)
            #pragma unroll
            for (int r = 0; r < 4; ++r)
                s += part[w][r][tid];
        atomicAdd(&pooled[b * E_DIM + tid], s);
    }

    if (!FUSED) return;

    // ---- last-block finalization (one block per batch does the matmul) ----
    __threadfence();                     // order our data atomics before counter
    __syncthreads();
    if (tid == 0) {
        const int old = atomicAdd(&counters[b], 1);
        last_flag = (old == WG_PER_B - 1);
    }
    __syncthreads();
    if (!last_flag) return;
    __threadfence();
    if (tid < E_DIM)
        pool2[tid] = __hip_atomic_load(&pooled[b * E_DIM + tid],
                                       __ATOMIC_RELAXED, __HIP_MEMORY_SCOPE_AGENT);
    __syncthreads();
    if (tid < 64) {
        const int e2 = 2 * tid;
        const float p0 = pool2[e2];
        const float p1 = pool2[e2 + 1];
        float acc[C_CLS];
        #pragma unroll
        for (int c = 0; c < C_CLS; ++c)
            acc[c] = fmaf(p0, W[e2 * C_CLS + c], p1 * W[(e2 + 1) * C_CLS + c]);
        #pragma unroll
        for (int c = 0; c < C_CLS; ++c)
            acc[c] = wave_sum_tail(acc[c]);
        if (tid == 63) {
            #pragma unroll
            for (int c = 0; c < C_CLS; ++c)
                out[b * C_CLS + c] = fmaf(acc[c], 1.0f / (float)T_LEN, bias[c]);
        }
    }
}

// Fallback final (two-dispatch path if ever needed).
__global__ __launch_bounds__(64) void qtc_final_a(
    const float* __restrict__ pooled,  // [B, E]
    const float* __restrict__ W,
    const float* __restrict__ bias,
    float*       __restrict__ out)
{
    const int b    = blockIdx.x;
    const int lane = threadIdx.x;
    const int e0   = 2 * lane;
    const float p0 = pooled[b * E_DIM + e0];
    const float p1 = pooled[b * E_DIM + e0 + 1];
    float acc[C_CLS];
    #pragma unroll
    for (int c = 0; c < C_CLS; ++c)
        acc[c] = fmaf(p0, W[e0 * C_CLS + c], p1 * W[(e0 + 1) * C_CLS + c]);
    #pragma unroll
    for (int c = 0; c < C_CLS; ++c)
        acc[c] = wave_sum_tail(acc[c]);
    if (lane == 63) {
        #pragma unroll
        for (int c = 0; c < C_CLS; ++c)
            out[b * C_CLS + c] = fmaf(acc[c], 1.0f / (float)T_LEN, bias[c]);
    }
}

extern "C" void kernel_launch(void* const* d_in, const int* in_sizes, int n_in,
                              void* d_out, int out_size, void* d_ws, size_t ws_size,
                              hipStream_t stream) {
    const int*   tokens = (const int*)  d_in[0];
    const float* emb    = (const float*)d_in[1];
    const float* g1     = (const float*)d_in[2];
    const float* b1     = (const float*)d_in[3];
    const float* g2     = (const float*)d_in[4];
    const float* b2     = (const float*)d_in[5];
    // d_in[6] = q_weights: provably unused by the reference
    const float* W      = (const float*)d_in[7];
    const float* bias   = (const float*)d_in[8];
    float* out = (float*)d_out;

    float* pooled   = (float*)d_ws;                       // 16 KB
    int*   counters = (int*)((char*)d_ws + B_SZ * E_DIM * sizeof(float));
    const size_t need = B_SZ * E_DIM * sizeof(float) + B_SZ * sizeof(int);

    hipMemsetAsync(d_ws, 0, need, stream);
    if (ws_size >= need) {
        qtc_main<true><<<NUM_WG, 256, 0, stream>>>(
            tokens, emb, g1, b1, g2, b2, W, bias, pooled, counters, out);
    } else {
        qtc_main<false><<<NUM_WG, 256, 0, stream>>>(
            tokens, emb, g1, b1, g2, b2, W, bias, pooled, counters, out);
        qtc_final_a<<<B_SZ, 64, 0, stream>>>(pooled, W, bias, out);
    }
}

// Round 14
// 28.316 us; speedup vs baseline: 5.5882x; 5.5882x over previous
//
#include <hip/hip_runtime.h>

// QuantumTextClassifier: embed+PE -> 4x {q=cumprod(cos(x)); x=LN(x+q); x=LN(x+q)}
// -> mean over T -> @W + b.
// r14 = EXACT revert to r9 (best measured: 28.2us).
// Mapping: FOUR rows per wave (16 lanes/row, 8 elems/lane = 4x float2).
//  - ALL LN params (128 floats = 64 VGPR) hoisted to registers once; NBLK loop
//    fully unrolled -> ZERO VMEM inside the hot chain.
//  - The wave's 2 tokens run as two independent chains through the unrolled
//    body (chain ILP x2), PE computed directly per position (no rotation).
//  - cumprod scan: 4 DPP muls + 1 shr; LN sums: 4 fused DPP adds; all
//    cross-lane on the VALU pipe (no LDS ops in hot loop).
// NOTE (r12/r13 lesson): codegen is bimodal. (256,8) or epilogue fusion flips
// the allocator into a 32-36 VGPR spill-everything mode (5x slower). Do not
// perturb: keep (256,4), params-in-regs, separate final kernel.
// Pooling: per-block LDS reduce -> disjoint partial row in d_ws (no atomics);
// qtc_final_p (256 thr, split w-loop) reduces 64 partials/batch + tiny matmul.

#define NBLK 4
#define E_DIM 128
#define T_LEN 2048
#define B_SZ 32
#define C_CLS 4
#define LN_EPS 1e-5f
#define WG_PER_B 64                         // workgroups per batch element
#define WAVES_PER_WG 4
#define NUM_WG (B_SZ * WG_PER_B)            // 2048

#define F_ONE 0x3F800000                    // bit pattern of 1.0f

typedef float v2f __attribute__((ext_vector_type(2)));
typedef float v4f __attribute__((ext_vector_type(4)));

// DPP move with old-value semantics (invalid/masked lanes -> OLD bits).
template <int CTRL, int RMASK, int OLDBITS>
__device__ __forceinline__ float dppf(float v) {
    return __int_as_float(__builtin_amdgcn_update_dpp(
        OLDBITS, __float_as_int(v), CTRL, RMASK, 0xF, false));
}

// Fused-add DPP step (bound_ctrl=1: invalid lanes contribute 0).
template <int CTRL>
__device__ __forceinline__ float dpp_add(float s) {
    return s + __int_as_float(__builtin_amdgcn_update_dpp(
        0, __float_as_int(s), CTRL, 0xF, 0xF, true));
}

// Sum over each 16-lane row; result broadcast to every lane of the row.
__device__ __forceinline__ float row16_sum(float s) {
    s = dpp_add<0xB1>(s);    // quad_perm [1,0,3,2]  ~ xor1
    s = dpp_add<0x4E>(s);    // quad_perm [2,3,0,1]  ~ xor2
    s = dpp_add<0x141>(s);   // row_half_mirror      ~ xor4
    s = dpp_add<0x140>(s);   // row_mirror           ~ xor8
    return s;
}

__device__ __forceinline__ v4f ld4(const float* p) {
    return *reinterpret_cast<const v4f*>(p);
}

// cumprod(cos(X)) along the 128-elem row (16 lanes x 4 v2f): Q = prefix prods.
__device__ __forceinline__ void cumq_v(const v2f* __restrict__ X,
                                       v2f* __restrict__ Q) {
    const float c0 = __cosf(X[0].x), c1 = __cosf(X[0].y);
    const float c2 = __cosf(X[1].x), c3 = __cosf(X[1].y);
    const float c4 = __cosf(X[2].x), c5 = __cosf(X[2].y);
    const float c6 = __cosf(X[3].x), c7 = __cosf(X[3].y);
    const float p23 = c2 * c3, p45 = c4 * c5, p67 = c6 * c7;
    const float P2 = c0 * c1;
    const float P4 = P2 * p23;
    const float P6 = P4 * p45;
    const float P8 = P6 * p67;         // lane's 8-elem product
    const float P3 = P2 * c2;
    const float P5 = P4 * c4;
    const float P7 = P6 * c6;
    float sc = P8;                     // inclusive scan over 16 lanes
    sc *= dppf<0x111, 0xF, F_ONE>(sc); // row_shr:1
    sc *= dppf<0x112, 0xF, F_ONE>(sc); // row_shr:2
    sc *= dppf<0x114, 0xF, F_ONE>(sc); // row_shr:4
    sc *= dppf<0x118, 0xF, F_ONE>(sc); // row_shr:8
    // exclusive: shift by 1; row-head lanes auto-get old=1.0
    const float ex = dppf<0x111, 0xF, F_ONE>(sc);
    const v2f exv = {ex, ex};
    Q[0] = exv * (v2f){c0, P2};
    Q[1] = exv * (v2f){P3, P4};
    Q[2] = exv * (v2f){P5, P6};
    Q[3] = exv * (v2f){P7, P8};
}

// LayerNorm over a 128-elem row held as 16 lanes x 4 float2.
__device__ __forceinline__ void ln8v(const v2f* __restrict__ Y,
                                     const v2f* __restrict__ g,
                                     const v2f* __restrict__ be,
                                     v2f* __restrict__ o) {
    v2f sv = (Y[0] + Y[1]) + (Y[2] + Y[3]);
    v2f qv = Y[0] * Y[0];
    qv = __builtin_elementwise_fma(Y[1], Y[1], qv);
    qv = __builtin_elementwise_fma(Y[2], Y[2], qv);
    qv = __builtin_elementwise_fma(Y[3], Y[3], qv);
    const float S  = row16_sum(sv.x + sv.y);
    const float S2 = row16_sum(qv.x + qv.y);
    const float mu  = S * (1.0f / 128.0f);
    const float var = fmaf(S2, 1.0f / 128.0f, -mu * mu);
    const float r   = rsqrtf(var + LN_EPS);
    const v2f muv = {mu, mu};
    const v2f rv  = {r, r};
    #pragma unroll
    for (int j = 0; j < 4; ++j)
        o[j] = __builtin_elementwise_fma((Y[j] - muv) * rv, g[j], be[j]);
}

template <bool ATOMIC>
__global__ __launch_bounds__(256, 4) void qtc_main(
    const int*   __restrict__ tokens,   // [B, T]
    const float* __restrict__ emb,      // [V, E]
    const float* __restrict__ g1,       // [NBLK, E]
    const float* __restrict__ b1,
    const float* __restrict__ g2,
    const float* __restrict__ b2,
    float*       __restrict__ outp)     // ATOMIC: pooled[B,E]; else part[NUM_WG,E]
{
    __shared__ float part[WAVES_PER_WG][4][E_DIM];   // 8 KB

    const int tid  = threadIdx.x;
    const int lane = tid & 63;
    const int wave = tid >> 6;
    const int b    = blockIdx.x / WG_PER_B;
    const int wgb  = blockIdx.x % WG_PER_B;
    const int row  = lane >> 4;          // which of the wave's 4 rows
    const int sub  = lane & 15;          // lane within row
    const int e0   = sub * 8;            // first of 8 contiguous elems
    const int wid  = wgb * WAVES_PER_WG + wave;     // [0, 256) within batch

    // ---- hoist ALL LN params into registers (64 VGPR) ----
    v2f G1[NBLK][4], B1[NBLK][4], G2[NBLK][4], B2[NBLK][4];
    #pragma unroll
    for (int i = 0; i < NBLK; ++i) {
        const v4f a1 = ld4(g1 + i * E_DIM + e0), a2 = ld4(g1 + i * E_DIM + e0 + 4);
        const v4f c1v = ld4(b1 + i * E_DIM + e0), c2v = ld4(b1 + i * E_DIM + e0 + 4);
        const v4f d1 = ld4(g2 + i * E_DIM + e0), d2 = ld4(g2 + i * E_DIM + e0 + 4);
        const v4f e1 = ld4(b2 + i * E_DIM + e0), e2 = ld4(b2 + i * E_DIM + e0 + 4);
        G1[i][0] = a1.xy;  G1[i][1] = a1.zw;  G1[i][2] = a2.xy;  G1[i][3] = a2.zw;
        B1[i][0] = c1v.xy; B1[i][1] = c1v.zw; B1[i][2] = c2v.xy; B1[i][3] = c2v.zw;
        G2[i][0] = d1.xy;  G2[i][1] = d1.zw;  G2[i][2] = d2.xy;  G2[i][3] = d2.zw;
        B2[i][0] = e1.xy;  B2[i][1] = e1.zw;  B2[i][2] = e2.xy;  B2[i][3] = e2.zw;
    }

    // ---- two token positions, PE computed directly (no rotation state) ----
    const int   ta  = wid * 4 + row;           // token index A (< 1024)
    const int   tix = b * T_LEN + ta;
    const int   tokA = tokens[tix];
    const int   tokB = tokens[tix + 1024];
    const float tfA = (float)ta;
    const float tfB = (float)(ta + 1024);

    v2f Xa[4], Xb[4];
    {
        const v4f a0 = ld4(&emb[tokA * E_DIM + e0]);
        const v4f a1 = ld4(&emb[tokA * E_DIM + e0 + 4]);
        const v4f b0 = ld4(&emb[tokB * E_DIM + e0]);
        const v4f b1v = ld4(&emb[tokB * E_DIM + e0 + 4]);
        const v2f ea[4] = {a0.xy, a0.zw, a1.xy, a1.zw};
        const v2f eb[4] = {b0.xy, b0.zw, b1v.xy, b1v.zw};
        #pragma unroll
        for (int j = 0; j < 4; ++j) {
            const float f = __expf(-(float)(e0 + 2 * j) * (9.210340371976184f / 128.0f));
            Xa[j] = ea[j] + (v2f){__sinf(tfA * f), __cosf(tfA * f)};
            Xb[j] = eb[j] + (v2f){__sinf(tfB * f), __cosf(tfB * f)};
        }
    }

    // ---- 4 transformer-sim blocks, two independent chains (A,B) ----
    #pragma unroll
    for (int i = 0; i < NBLK; ++i) {
        v2f Qa[4], Qb[4], Y[4];
        cumq_v(Xa, Qa);
        cumq_v(Xb, Qb);
        #pragma unroll
        for (int k = 0; k < 4; ++k) Y[k] = Xa[k] + Qa[k];
        ln8v(Y, G1[i], B1[i], Xa);
        #pragma unroll
        for (int k = 0; k < 4; ++k) Y[k] = Xb[k] + Qb[k];
        ln8v(Y, G1[i], B1[i], Xb);
        #pragma unroll
        for (int k = 0; k < 4; ++k) Y[k] = Xa[k] + Qa[k];
        ln8v(Y, G2[i], B2[i], Xa);
        #pragma unroll
        for (int k = 0; k < 4; ++k) Y[k] = Xb[k] + Qb[k];
        ln8v(Y, G2[i], B2[i], Xb);
    }

    // ---- block-level pooling ----
    const v4f lo = {Xa[0].x + Xb[0].x, Xa[0].y + Xb[0].y,
                    Xa[1].x + Xb[1].x, Xa[1].y + Xb[1].y};
    const v4f hi = {Xa[2].x + Xb[2].x, Xa[2].y + Xb[2].y,
                    Xa[3].x + Xb[3].x, Xa[3].y + Xb[3].y};
    *reinterpret_cast<v4f*>(&part[wave][row][e0])     = lo;
    *reinterpret_cast<v4f*>(&part[wave][row][e0 + 4]) = hi;
    __syncthreads();
    if (tid < E_DIM) {
        float s = 0.0f;
        #pragma unroll
        for (int w = 0; w < WAVES_PER_WG; ++w)
            #pragma unroll
            for (int r = 0; r < 4; ++r)
                s += part[w][r][tid];
        if (ATOMIC)
            atomicAdd(&outp[b * E_DIM + tid], s);
        else
            outp[blockIdx.x * E_DIM + tid] = s;   // disjoint partial row
    }
}

// Fused-add DPP over full wave (for the final reduce kernels).
__device__ __forceinline__ float wave_sum_tail(float s) {
    s = dpp_add<0xB1>(s);
    s = dpp_add<0x4E>(s);
    s = dpp_add<0x141>(s);
    s = dpp_add<0x140>(s);
    s = s + __int_as_float(__builtin_amdgcn_update_dpp(
        0, __float_as_int(s), 0x142, 0xA, 0xF, true));   // row_bcast15 -> rows 1,3
    s = s + __int_as_float(__builtin_amdgcn_update_dpp(
        0, __float_as_int(s), 0x143, 0xC, 0xF, true));   // row_bcast31 -> rows 2,3
    return s;                                            // total in lane 63
}

// Partials path: reduce 64 WG-partials per batch (w-loop split across 2 half-
// blocks of threads), then tiny matmul on wave 0.
__global__ __launch_bounds__(256) void qtc_final_p(
    const float* __restrict__ part,    // [NUM_WG, E]
    const float* __restrict__ W,       // [E, C]
    const float* __restrict__ bias,    // [C]
    float*       __restrict__ out)     // [B, C]
{
    __shared__ float red[2][E_DIM];
    __shared__ float pooled[E_DIM];
    const int b   = blockIdx.x;
    const int tid = threadIdx.x;
    const int e   = tid & 127;
    const int h   = tid >> 7;          // 0 or 1: which half of the w-range
    const float* base = part + (size_t)b * WG_PER_B * E_DIM + e;
    float s = 0.0f;
    #pragma unroll 8
    for (int w = h * 32; w < h * 32 + 32; ++w)
        s += base[w * E_DIM];
    red[h][e] = s;
    __syncthreads();
    if (tid < E_DIM)
        pooled[tid] = red[0][tid] + red[1][tid];
    __syncthreads();
    if (tid < 64) {
        const int lane = tid;
        const int e0 = 2 * lane;
        const float p0 = pooled[e0];
        const float p1 = pooled[e0 + 1];
        float acc[C_CLS];
        #pragma unroll
        for (int c = 0; c < C_CLS; ++c)
            acc[c] = fmaf(p0, W[e0 * C_CLS + c], p1 * W[(e0 + 1) * C_CLS + c]);
        #pragma unroll
        for (int c = 0; c < C_CLS; ++c)
            acc[c] = wave_sum_tail(acc[c]);
        if (lane == 63) {
            #pragma unroll
            for (int c = 0; c < C_CLS; ++c)
                out[b * C_CLS + c] = fmaf(acc[c], 1.0f / (float)T_LEN, bias[c]);
        }
    }
}

// Atomic-pooled fallback final (pooled[B,E] already summed).
__global__ __launch_bounds__(64) void qtc_final_a(
    const float* __restrict__ pooled,  // [B, E]
    const float* __restrict__ W,
    const float* __restrict__ bias,
    float*       __restrict__ out)
{
    const int b    = blockIdx.x;
    const int lane = threadIdx.x;
    const int e0   = 2 * lane;
    const float p0 = pooled[b * E_DIM + e0];
    const float p1 = pooled[b * E_DIM + e0 + 1];
    float acc[C_CLS];
    #pragma unroll
    for (int c = 0; c < C_CLS; ++c)
        acc[c] = fmaf(p0, W[e0 * C_CLS + c], p1 * W[(e0 + 1) * C_CLS + c]);
    #pragma unroll
    for (int c = 0; c < C_CLS; ++c)
        acc[c] = wave_sum_tail(acc[c]);
    if (lane == 63) {
        #pragma unroll
        for (int c = 0; c < C_CLS; ++c)
            out[b * C_CLS + c] = fmaf(acc[c], 1.0f / (float)T_LEN, bias[c]);
    }
}

extern "C" void kernel_launch(void* const* d_in, const int* in_sizes, int n_in,
                              void* d_out, int out_size, void* d_ws, size_t ws_size,
                              hipStream_t stream) {
    const int*   tokens = (const int*)  d_in[0];
    const float* emb    = (const float*)d_in[1];
    const float* g1     = (const float*)d_in[2];
    const float* b1     = (const float*)d_in[3];
    const float* g2     = (const float*)d_in[4];
    const float* b2     = (const float*)d_in[5];
    // d_in[6] = q_weights: provably unused by the reference
    const float* W      = (const float*)d_in[7];
    const float* bias   = (const float*)d_in[8];
    float* out = (float*)d_out;

    const size_t part_bytes = (size_t)NUM_WG * E_DIM * sizeof(float);  // 1 MB
    if (ws_size >= part_bytes) {
        float* part = (float*)d_ws;
        qtc_main<false><<<NUM_WG, 256, 0, stream>>>(tokens, emb, g1, b1, g2, b2, part);
        qtc_final_p<<<B_SZ, 256, 0, stream>>>(part, W, bias, out);
    } else {
        float* pooled = (float*)d_ws;  // 16 KB
        hipMemsetAsync(pooled, 0, B_SZ * E_DIM * sizeof(float), stream);
        qtc_main<true><<<NUM_WG, 256, 0, stream>>>(tokens, emb, g1, b1, g2, b2, pooled);
        qtc_final_a<<<B_SZ, 64, 0, stream>>>(pooled, W, bias, out);
    }
}